// Round 1
// baseline (49.993 us; speedup 1.0000x reference)
//
#include <hip/hip_runtime.h>
#include <math.h>

// Problem constants (from reference): query [4,32,64,64] f32, key [4,32,64,192] f32
#define B 4
#define C 32
#define H 64
#define WQ 64
#define WK 192
#define NP 129                  // P = 192 - 64 + 1
#define ELEMS (C * H * WQ)      // 131072 elements reduced per (b,p)

// Kernel A: one block per (b,p). Block-reduce sum |key[b,c,h,w+p] - query[b,c,h,w]|.
__global__ __launch_bounds__(256) void patch_l1_sums(const float* __restrict__ query,
                                                     const float* __restrict__ key,
                                                     float* __restrict__ sums) {
    const int bid = blockIdx.x;        // 0 .. B*NP-1
    const int b = bid / NP;
    const int p = bid - b * NP;

    const float* __restrict__ qb = query + (size_t)b * ELEMS;
    const float* __restrict__ kb = key + (size_t)b * C * H * WK + p;

    float acc = 0.0f;
    // Each thread handles groups of 4 consecutive w. 131072/4 = 32768 groups.
    for (int g = threadIdx.x; g < ELEMS / 4; g += 256) {
        const int e = g << 2;                 // element index: c*4096 + h*64 + w
        const int w = e & 63;
        const int h = (e >> 6) & 63;
        const int c = e >> 12;
        const float4 q4 = *reinterpret_cast<const float4*>(qb + e);
        const float* kp = kb + ((c * H + h) * WK + w);   // shifted by p (unaligned -> scalar)
        acc += fabsf(kp[0] - q4.x) + fabsf(kp[1] - q4.y)
             + fabsf(kp[2] - q4.z) + fabsf(kp[3] - q4.w);
    }

    __shared__ float red[256];
    red[threadIdx.x] = acc;
    __syncthreads();
    #pragma unroll
    for (int s = 128; s > 0; s >>= 1) {
        if (threadIdx.x < s) red[threadIdx.x] += red[threadIdx.x + s];
        __syncthreads();
    }
    if (threadIdx.x == 0) sums[bid] = red[0];
}

// Kernel B: one block per batch b. y = sum/ELEMS; min + first-index argmin over p.
// Output layout (all written as float32, 9 elems):
//   out[0..3] = hard_indices[b];  out[4] = P (=129);  out[5..8] = relevance_maps[b]
__global__ __launch_bounds__(256) void patch_l1_finalize(const float* __restrict__ sums,
                                                         float* __restrict__ out) {
    const int b = blockIdx.x;
    const int t = threadIdx.x;

    float y = INFINITY;
    int idx = NP;   // sentinel larger than any valid index
    if (t < NP) {
        y = sums[b * NP + t] * (1.0f / (float)ELEMS);
        idx = t;
    }

    __shared__ float sy[256];
    __shared__ int   si[256];
    sy[t] = y;
    si[t] = idx;
    __syncthreads();
    #pragma unroll
    for (int s = 128; s > 0; s >>= 1) {
        if (t < s) {
            const float yo = sy[t + s];
            const int   io = si[t + s];
            if (yo < sy[t] || (yo == sy[t] && io < si[t])) {
                sy[t] = yo;
                si[t] = io;
            }
        }
        __syncthreads();
    }

    if (t == 0) {
        out[b]     = (float)si[0];     // hard_indices as float
        out[5 + b] = sy[0];            // relevance min
        if (b == 0) out[4] = (float)NP;
    }
}

extern "C" void kernel_launch(void* const* d_in, const int* in_sizes, int n_in,
                              void* d_out, int out_size, void* d_ws, size_t ws_size,
                              hipStream_t stream) {
    const float* query = (const float*)d_in[0];
    const float* key   = (const float*)d_in[1];
    float* out  = (float*)d_out;
    float* sums = (float*)d_ws;   // B*NP = 516 floats

    patch_l1_sums<<<B * NP, 256, 0, stream>>>(query, key, sums);
    patch_l1_finalize<<<B, 256, 0, stream>>>(sums, out);
}

// Round 2
// 35.140 us; speedup vs baseline: 1.4227x; 1.4227x over previous
//
#include <hip/hip_runtime.h>
#include <math.h>

// query [4,32,64,64] f32, key [4,32,64,192] f32
#define B 4
#define C 32
#define H 64
#define WQ 64
#define WK 192
#define NP 129                   // P = 192 - 64 + 1
#define ROWS (C * H)             // 2048 rows per batch, row = (c,h)
#define ELEMS (ROWS * WQ)        // 131072 elements reduced per (b,p)
#define GB 256                   // blocks per batch
#define SLOTS (GB * 4)           // wave-slots per batch (4 waves/block)
#define RPW (ROWS / SLOTS)       // rows per wave = 2

// Kernel A: wave processes rows; lane l accumulates p=l (acc0), p=l+64 (acc1);
// p=128 via acc2 (w=lane, wave-reduced). Block-reduce in LDS, one atomic set/block.
__global__ __launch_bounds__(256, 4) void patch_l1_sums(const float* __restrict__ query,
                                                        const float* __restrict__ key,
                                                        float* __restrict__ sums) {
    const int bid  = blockIdx.x;
    const int b    = bid >> 8;           // / GB
    const int g    = bid & (GB - 1);
    const int t    = threadIdx.x;
    const int wv   = t >> 6;
    const int lane = t & 63;
    const int slot = g * 4 + wv;

    const float* __restrict__ qb = query + (size_t)b * (ROWS * WQ);
    const float* __restrict__ kb = key   + (size_t)b * (ROWS * WK);

    float acc0 = 0.f, acc1 = 0.f, acc2 = 0.f;

    for (int s = 0; s < RPW; ++s) {
        // row index is wave-uniform; make it provably so -> scalar loads for q
        const int r = __builtin_amdgcn_readfirstlane(slot + s * SLOTS);
        const float* __restrict__ qr = qb + r * WQ;
        const float* __restrict__ kr = kb + r * WK;

        #pragma unroll
        for (int gi = 0; gi < 16; ++gi) {
            const int w = gi * 4;
            const float4 qv = *reinterpret_cast<const float4*>(qr + w);          // uniform -> s_load
            const float4 ka = *reinterpret_cast<const float4*>(kr + w + lane);       // window p=lane
            const float4 kc = *reinterpret_cast<const float4*>(kr + w + lane + 64);  // window p=lane+64
            acc0 += fabsf(ka.x - qv.x) + fabsf(ka.y - qv.y)
                  + fabsf(ka.z - qv.z) + fabsf(ka.w - qv.w);
            acc1 += fabsf(kc.x - qv.x) + fabsf(kc.y - qv.y)
                  + fabsf(kc.z - qv.z) + fabsf(kc.w - qv.w);
        }
        acc2 += fabsf(kr[128 + lane] - qr[lane]);                                // p=128, w=lane
    }

    // wave-reduce the p=128 accumulator across 64 lanes
    #pragma unroll
    for (int m = 32; m; m >>= 1) acc2 += __shfl_xor(acc2, m, 64);

    __shared__ float red[4][NP];
    red[wv][lane]      = acc0;
    red[wv][64 + lane] = acc1;
    if (lane == 0) red[wv][128] = acc2;
    __syncthreads();

    if (t < NP) {
        const float v = red[0][t] + red[1][t] + red[2][t] + red[3][t];
        atomicAdd(&sums[b * NP + t], v);
    }
}

// Kernel B: one block per batch. y = sum/ELEMS; min + first-index argmin over p.
// out[0..3]=hard_indices (as f32); out[4]=P; out[5..8]=relevance min
__global__ __launch_bounds__(256) void patch_l1_finalize(const float* __restrict__ sums,
                                                         float* __restrict__ out) {
    const int b = blockIdx.x;
    const int t = threadIdx.x;

    float y = INFINITY;
    int idx = NP;
    if (t < NP) {
        y = sums[b * NP + t] * (1.0f / (float)ELEMS);
        idx = t;
    }

    __shared__ float sy[256];
    __shared__ int   si[256];
    sy[t] = y;
    si[t] = idx;
    __syncthreads();
    #pragma unroll
    for (int s = 128; s > 0; s >>= 1) {
        if (t < s) {
            const float yo = sy[t + s];
            const int   io = si[t + s];
            if (yo < sy[t] || (yo == sy[t] && io < si[t])) {
                sy[t] = yo;
                si[t] = io;
            }
        }
        __syncthreads();
    }

    if (t == 0) {
        out[b]     = (float)si[0];
        out[5 + b] = sy[0];
        if (b == 0) out[4] = (float)NP;
    }
}

extern "C" void kernel_launch(void* const* d_in, const int* in_sizes, int n_in,
                              void* d_out, int out_size, void* d_ws, size_t ws_size,
                              hipStream_t stream) {
    const float* query = (const float*)d_in[0];
    const float* key   = (const float*)d_in[1];
    float* out  = (float*)d_out;
    float* sums = (float*)d_ws;   // B*NP = 516 floats, accumulated via atomics

    hipMemsetAsync(sums, 0, B * NP * sizeof(float), stream);
    patch_l1_sums<<<B * GB, 256, 0, stream>>>(query, key, sums);
    patch_l1_finalize<<<B, 256, 0, stream>>>(sums, out);
}

// Round 3
// 30.897 us; speedup vs baseline: 1.6181x; 1.1373x over previous
//
#include <hip/hip_runtime.h>
#include <math.h>

// query [4,32,64,64] f32, key [4,32,64,192] f32
#define B 4
#define C 32
#define H 64
#define WQ 64
#define WK 192
#define NP 129                   // P = 192 - 64 + 1
#define ROWS (C * H)             // 2048 rows per batch, row = (c,h)
#define ELEMS (ROWS * WQ)        // 131072 elements reduced per (b,p)
#define GB 128                   // blocks per batch
#define WPB 4                    // waves per block
#define RPW (ROWS / (GB * WPB))  // rows per wave = 4

// Kernel A: lane l owns shifts p=2l and p=2l+1. One sequential scan of the
// k-row (staged in a wave-private LDS slice) feeds both accumulators; q values
// are wave-uniform scalars (SGPR operands). p=128 is a per-row extra term.
__global__ __launch_bounds__(256, 2) void patch_l1_sums(const float* __restrict__ query,
                                                        const float* __restrict__ key,
                                                        float* __restrict__ sums) {
    __shared__ __align__(16) float kbuf[WPB][WK];   // 768 B per wave, wave-private
    __shared__ float red[WPB][NP];

    const int bid  = blockIdx.x;
    const int b    = bid >> 7;          // / GB
    const int g    = bid & (GB - 1);
    const int t    = threadIdx.x;
    const int wv   = t >> 6;
    const int lane = t & 63;
    // wave-uniform slot (readfirstlane -> enables s_load scalarization of q)
    const int slot = __builtin_amdgcn_readfirstlane(g * WPB + (t >> 6));
    const int r0   = slot * RPW;

    const float* __restrict__ qb = query + (size_t)b * ELEMS;
    const float* __restrict__ kb = key   + (size_t)b * ROWS * WK;

    float acc_a = 0.f, acc_b = 0.f, acc2 = 0.f;

    // prefetch row r0's k into registers (lane<48 x float4 = 768 B)
    float4 kst = make_float4(0.f, 0.f, 0.f, 0.f);
    if (lane < 48) kst = *reinterpret_cast<const float4*>(kb + (size_t)r0 * WK + lane * 4);

    #pragma unroll
    for (int i = 0; i < RPW; ++i) {
        const int r = r0 + i;
        // stage current row into this wave's LDS slice
        if (lane < 48) *reinterpret_cast<float4*>(&kbuf[wv][lane * 4]) = kst;
        // issue next row's global prefetch (overlaps compute below)
        if (i + 1 < RPW && lane < 48)
            kst = *reinterpret_cast<const float4*>(kb + (size_t)(r + 1) * WK + lane * 4);

        const float* __restrict__ qr = qb + r * WQ;   // uniform -> s_load
        const float  ql = qr[lane];                   // per-lane (for p=128)

        // scan x = 2*lane + s, s = 0..65 in b64 pairs
        #pragma unroll
        for (int si = 0; si < 33; ++si) {
            const int s = si * 2;
            const float2 kk = *reinterpret_cast<const float2*>(&kbuf[wv][2 * lane + s]);
            if (si < 32) {
                acc_a += fabsf(kk.x - qr[s]);       // p=2l,   w=s
                acc_a += fabsf(kk.y - qr[s + 1]);   // p=2l,   w=s+1
                acc_b += fabsf(kk.y - qr[s]);       // p=2l+1, w=s
                if (si > 0) acc_b += fabsf(kk.x - qr[s - 1]);  // p=2l+1, w=s-1
            } else {
                acc_b += fabsf(kk.x - qr[63]);      // s=64: p=2l+1, w=63
            }
        }
        // p = 128: k[128+lane] vs q[lane]
        acc2 += fabsf(kbuf[wv][128 + lane] - ql);
    }

    // wave-reduce the p=128 accumulator
    #pragma unroll
    for (int m = 32; m; m >>= 1) acc2 += __shfl_xor(acc2, m, 64);

    red[wv][2 * lane]     = acc_a;
    red[wv][2 * lane + 1] = acc_b;
    if (lane == 0) red[wv][128] = acc2;
    __syncthreads();

    if (t < NP) {
        const float v = red[0][t] + red[1][t] + red[2][t] + red[3][t];
        atomicAdd(&sums[b * NP + t], v);
    }
}

// Kernel B: one block per batch. y = sum/ELEMS; min + first-index argmin over p.
// out[0..3]=hard_indices (as f32); out[4]=P; out[5..8]=relevance min
__global__ __launch_bounds__(256) void patch_l1_finalize(const float* __restrict__ sums,
                                                         float* __restrict__ out) {
    const int b = blockIdx.x;
    const int t = threadIdx.x;

    float y = INFINITY;
    int idx = NP;
    if (t < NP) {
        y = sums[b * NP + t] * (1.0f / (float)ELEMS);
        idx = t;
    }

    __shared__ float sy[256];
    __shared__ int   si[256];
    sy[t] = y;
    si[t] = idx;
    __syncthreads();
    #pragma unroll
    for (int s = 128; s > 0; s >>= 1) {
        if (t < s) {
            const float yo = sy[t + s];
            const int   io = si[t + s];
            if (yo < sy[t] || (yo == sy[t] && io < si[t])) {
                sy[t] = yo;
                si[t] = io;
            }
        }
        __syncthreads();
    }

    if (t == 0) {
        out[b]     = (float)si[0];
        out[5 + b] = sy[0];
        if (b == 0) out[4] = (float)NP;
    }
}

extern "C" void kernel_launch(void* const* d_in, const int* in_sizes, int n_in,
                              void* d_out, int out_size, void* d_ws, size_t ws_size,
                              hipStream_t stream) {
    const float* query = (const float*)d_in[0];
    const float* key   = (const float*)d_in[1];
    float* out  = (float*)d_out;
    float* sums = (float*)d_ws;   // B*NP = 516 floats, accumulated via atomics

    hipMemsetAsync(sums, 0, B * NP * sizeof(float), stream);
    patch_l1_sums<<<B * GB, 256, 0, stream>>>(query, key, sums);
    patch_l1_finalize<<<B, 256, 0, stream>>>(sums, out);
}

// Round 4
// 19.984 us; speedup vs baseline: 2.5016x; 1.5461x over previous
//
#include <hip/hip_runtime.h>
#include <math.h>

// query [4,32,64,64] f32, key [4,32,64,192] f32
#define B 4
#define C 32
#define H 64
#define WQ 64
#define WK 192
#define NP 129                    // P = 192 - 64 + 1
#define ROWS (C * H)              // 2048 rows per batch
#define ELEMS (ROWS * WQ)         // 131072 elements per (b,p)
#define GB 256                    // blocks per batch
#define WPB 4                     // waves per block
#define RPW (ROWS / (GB * WPB))   // rows per wave = 2
#define PSTRIDE 132               // padded partial-row stride (floats)

// Kernel A: lane l owns shifts p=2l, p=2l+1. Both of the wave's rows are staged
// into a wave-private LDS slice up-front; one fully-unrolled loop interleaves the
// two rows' scans (2 independent ds_read_b64 + 4 independent acc chains per step).
// q operands are wave-uniform (readfirstlane'd row index -> s_load, SMEM pipe).
// Each block writes its own 129 partial sums -- no atomics, no memset.
__global__ __launch_bounds__(256, 4) void patch_l1_partial(const float* __restrict__ query,
                                                           const float* __restrict__ key,
                                                           float* __restrict__ part) {
    __shared__ __align__(16) float kbuf[WPB][RPW * WK];   // 1.5 KB per wave
    __shared__ float red[WPB][NP];

    const int bid  = blockIdx.x;
    const int b    = bid >> 8;           // / GB
    const int g    = bid & (GB - 1);
    const int t    = threadIdx.x;
    const int wv   = t >> 6;
    const int lane = t & 63;
    const int slot = __builtin_amdgcn_readfirstlane(g * WPB + (t >> 6));
    const int r0   = slot * RPW;         // this wave's two rows

    const float* __restrict__ qb = query + (size_t)b * ELEMS;
    const float* __restrict__ kb = key   + (size_t)b * ROWS * WK + (size_t)r0 * WK;

    // stage both k-rows into wave-private LDS (lane<48: one float4 per row)
    if (lane < 48) {
        const float4 k0 = *reinterpret_cast<const float4*>(kb + lane * 4);
        const float4 k1 = *reinterpret_cast<const float4*>(kb + WK + lane * 4);
        *reinterpret_cast<float4*>(&kbuf[wv][lane * 4])      = k0;
        *reinterpret_cast<float4*>(&kbuf[wv][WK + lane * 4]) = k1;
    }
    // per-lane q values for the p=128 terms (L1/L2-hot)
    const float q0l = qb[(size_t)r0 * WQ + lane];
    const float q1l = qb[(size_t)(r0 + 1) * WQ + lane];

    const float* __restrict__ q0 = qb + (size_t)r0 * WQ;         // uniform -> s_load
    const float* __restrict__ q1 = qb + (size_t)(r0 + 1) * WQ;   // uniform -> s_load
    const float* __restrict__ k0 = &kbuf[wv][0];
    const float* __restrict__ k1 = &kbuf[wv][WK];

    float a0 = 0.f, b0 = 0.f, a1 = 0.f, b1 = 0.f, acc2 = 0.f;

    #pragma unroll
    for (int si = 0; si < 33; ++si) {
        const int s = si * 2;
        const float2 ka = *reinterpret_cast<const float2*>(&k0[2 * lane + s]);
        const float2 kc = *reinterpret_cast<const float2*>(&k1[2 * lane + s]);
        if (si < 32) {
            a0 += fabsf(ka.x - q0[s]) + fabsf(ka.y - q0[s + 1]);
            a1 += fabsf(kc.x - q1[s]) + fabsf(kc.y - q1[s + 1]);
            b0 += fabsf(ka.y - q0[s]);
            b1 += fabsf(kc.y - q1[s]);
            if (si > 0) {
                b0 += fabsf(ka.x - q0[s - 1]);
                b1 += fabsf(kc.x - q1[s - 1]);
            }
        } else {   // s = 64: only the p=2l+1 (w=63) term
            b0 += fabsf(ka.x - q0[63]);
            b1 += fabsf(kc.x - q1[63]);
        }
    }
    // p = 128 terms: k[128+lane] vs q[lane], both rows
    acc2 += fabsf(k0[128 + lane] - q0l);
    acc2 += fabsf(k1[128 + lane] - q1l);

    // wave-reduce the p=128 accumulator across 64 lanes
    #pragma unroll
    for (int m = 32; m; m >>= 1) acc2 += __shfl_xor(acc2, m, 64);

    red[wv][2 * lane]     = a0 + a1;
    red[wv][2 * lane + 1] = b0 + b1;
    if (lane == 0) red[wv][128] = acc2;
    __syncthreads();

    if (t < NP)
        part[(size_t)bid * PSTRIDE + t] = red[0][t] + red[1][t] + red[2][t] + red[3][t];
}

// Kernel B: one block per batch. Reduce 256 block-partials per p, then
// min + first-index argmin over p.
// out[0..3]=hard_indices (f32); out[4]=P; out[5..8]=relevance min
__global__ __launch_bounds__(256) void patch_l1_final(const float* __restrict__ part,
                                                      float* __restrict__ out) {
    const int b = blockIdx.x;
    const int t = threadIdx.x;

    float y = INFINITY;
    int idx = NP;
    if (t < NP) {
        const float* __restrict__ p0 = part + (size_t)b * GB * PSTRIDE + t;
        float s0 = 0.f, s1 = 0.f, s2 = 0.f, s3 = 0.f;
        #pragma unroll 4
        for (int g = 0; g < GB; g += 4) {
            s0 += p0[(g + 0) * PSTRIDE];
            s1 += p0[(g + 1) * PSTRIDE];
            s2 += p0[(g + 2) * PSTRIDE];
            s3 += p0[(g + 3) * PSTRIDE];
        }
        y = ((s0 + s1) + (s2 + s3)) * (1.0f / (float)ELEMS);
        idx = t;
    }

    __shared__ float sy[256];
    __shared__ int   si[256];
    sy[t] = y;
    si[t] = idx;
    __syncthreads();
    #pragma unroll
    for (int s = 128; s > 0; s >>= 1) {
        if (t < s) {
            const float yo = sy[t + s];
            const int   io = si[t + s];
            if (yo < sy[t] || (yo == sy[t] && io < si[t])) {
                sy[t] = yo;
                si[t] = io;
            }
        }
        __syncthreads();
    }

    if (t == 0) {
        out[b]     = (float)si[0];
        out[5 + b] = sy[0];
        if (b == 0) out[4] = (float)NP;
    }
}

extern "C" void kernel_launch(void* const* d_in, const int* in_sizes, int n_in,
                              void* d_out, int out_size, void* d_ws, size_t ws_size,
                              hipStream_t stream) {
    const float* query = (const float*)d_in[0];
    const float* key   = (const float*)d_in[1];
    float* out  = (float*)d_out;
    float* part = (float*)d_ws;   // B*GB*PSTRIDE floats = 540 KB, block-owned (no atomics)

    patch_l1_partial<<<B * GB, 256, 0, stream>>>(query, key, part);
    patch_l1_final<<<B, 256, 0, stream>>>(part, out);
}